// Round 1
// baseline (24.716 us; speedup 1.0000x reference)
//
#include <hip/hip_runtime.h>
#include <hip/hip_bf16.h>

using f32x4  = __attribute__((ext_vector_type(4))) float;
using bf16x8 = __attribute__((ext_vector_type(8))) short;

constexpr int   G_NUM = 256;
constexpr int   NAUG  = 256;
constexpr int   NORIG = 512;
constexpr int   DIM   = 128;
constexpr float INV_T = 10.0f;

// round-to-nearest-even f32 -> bf16 bits
__device__ __forceinline__ short f32_to_bf16_bits(float x) {
    unsigned u = __float_as_uint(x);
    u += 0x7fffu + ((u >> 16) & 1u);
    return (short)(u >> 16);
}

// Kernel 1: one block per graph. 512 threads = 8 waves.
// Wave w owns output rows [w*32, w*32+32) of the 256x256 score matrix.
// Student fragments live in registers; teacher (gathered+normalized, bf16)
// lives in a 64KB XOR-swizzled LDS tile.
__global__ __launch_bounds__(512, 1) void nlcl_main(
    const float* __restrict__ student,
    const float* __restrict__ teacher,
    const int*   __restrict__ kept,
    float*       __restrict__ graph_sums)
{
    __shared__ short t_lds[NAUG * DIM]; // [256 rows][128 bf16], swizzled, 64KB

    const int g    = blockIdx.x;
    const int tid  = threadIdx.x;
    const int lane = tid & 63;
    const int wave = tid >> 6;        // 0..7

    const float* s_base = student + (size_t)g * NAUG * DIM;
    const float* t_base = teacher + (size_t)g * NORIG * DIM;
    const int*   k_base = kept + g * NAUG;

    const int ccol  = lane & 15;      // col within 16x16 tile / frag row select
    const int cquad = lane >> 4;      // 0..3, selects k-subchunk

    // ---------------- Phase 1: student -> normalized bf16 A-fragments ----------------
    // frag(rt,kc): lane holds s[row = w*32+rt*16+ccol][d = kc*32+cquad*8 + 0..7]
    bf16x8 afrag[2][4];
    #pragma unroll
    for (int rt = 0; rt < 2; ++rt) {
        const int row = wave * 32 + rt * 16 + ccol;
        const float* rp = s_base + row * DIM;
        float sf[4][8];
        #pragma unroll
        for (int kc = 0; kc < 4; ++kc) {
            const int d0 = kc * 32 + cquad * 8;
            const float4 a = *reinterpret_cast<const float4*>(rp + d0);
            const float4 b = *reinterpret_cast<const float4*>(rp + d0 + 4);
            sf[kc][0] = a.x; sf[kc][1] = a.y; sf[kc][2] = a.z; sf[kc][3] = a.w;
            sf[kc][4] = b.x; sf[kc][5] = b.y; sf[kc][6] = b.z; sf[kc][7] = b.w;
        }
        float ss = 0.f;
        #pragma unroll
        for (int kc = 0; kc < 4; ++kc)
            #pragma unroll
            for (int e = 0; e < 8; ++e) ss += sf[kc][e] * sf[kc][e];
        // lanes {l, l^16, l^32, l^48} share a row -> combine
        ss += __shfl_xor(ss, 16);
        ss += __shfl_xor(ss, 32);
        const float scale = rsqrtf(fmaxf(ss, 1e-24f));
        #pragma unroll
        for (int kc = 0; kc < 4; ++kc)
            #pragma unroll
            for (int e = 0; e < 8; ++e)
                afrag[rt][kc][e] = f32_to_bf16_bits(sf[kc][e] * scale);
    }

    // ---------------- Phase 2: teacher gather+normalize -> swizzled bf16 LDS ----------------
    // half-wave per row: 32 lanes x float4 = 512B row
    {
        const int hw = tid >> 5;      // 0..15
        const int hl = tid & 31;
        char* tl = reinterpret_cast<char*>(t_lds);
        #pragma unroll 4
        for (int it = 0; it < 16; ++it) {
            const int j   = it * 16 + hw;          // 0..255
            const int src = k_base[j];             // 0..NORIG-1
            const float* rp = t_base + (size_t)src * DIM;
            const float4 v = *reinterpret_cast<const float4*>(rp + hl * 4);
            float ss = v.x * v.x + v.y * v.y + v.z * v.z + v.w * v.w;
            ss += __shfl_xor(ss, 1);
            ss += __shfl_xor(ss, 2);
            ss += __shfl_xor(ss, 4);
            ss += __shfl_xor(ss, 8);
            ss += __shfl_xor(ss, 16);
            const float scale = rsqrtf(fmaxf(ss, 1e-24f));
            short4 o;
            o.x = f32_to_bf16_bits(v.x * scale);
            o.y = f32_to_bf16_bits(v.y * scale);
            o.z = f32_to_bf16_bits(v.z * scale);
            o.w = f32_to_bf16_bits(v.w * scale);
            // row j, bytes [hl*8, hl*8+8), XOR-swizzled within row (bits 4..6)
            const int byte = j * 256 + ((hl * 8) ^ ((j & 7) << 4));
            *reinterpret_cast<short4*>(tl + byte) = o;
        }
    }
    __syncthreads();

    // ---------------- Phase 3: MFMA + online softmax-sum + diagonal ----------------
    float sumexp[2][4] = {{0.f, 0.f, 0.f, 0.f}, {0.f, 0.f, 0.f, 0.f}};
    float diagsum = 0.f;
    const char* tl = reinterpret_cast<const char*>(t_lds);

    for (int ct = 0; ct < 16; ++ct) {
        f32x4 acc0 = {0.f, 0.f, 0.f, 0.f};
        f32x4 acc1 = {0.f, 0.f, 0.f, 0.f};
        const int j = ct * 16 + ccol;             // teacher row = score col
        #pragma unroll
        for (int kc = 0; kc < 4; ++kc) {
            const int byte = j * 256 + (((kc * 64) + (cquad * 16)) ^ ((j & 7) << 4));
            const bf16x8 b = *reinterpret_cast<const bf16x8*>(tl + byte);
            acc0 = __builtin_amdgcn_mfma_f32_16x16x32_bf16(afrag[0][kc], b, acc0, 0, 0, 0);
            acc1 = __builtin_amdgcn_mfma_f32_16x16x32_bf16(afrag[1][kc], b, acc1, 0, 0, 0);
        }
        const int col = j;
        #pragma unroll
        for (int reg = 0; reg < 4; ++reg) {
            const int row0 = wave * 32 + cquad * 4 + reg;   // rt=0
            const int row1 = row0 + 16;                     // rt=1
            const float l0 = acc0[reg] * INV_T;
            const float l1 = acc1[reg] * INV_T;
            sumexp[0][reg] += __expf(l0);
            sumexp[1][reg] += __expf(l1);
            if (col == row0) diagsum += l0;
            if (col == row1) diagsum += l1;
        }
    }

    // ---------------- Phase 4: reduce: sum_i [ log(sumexp_i) ] - sum_i diag_i ----------------
    float ce = 0.f;
    #pragma unroll
    for (int rt = 0; rt < 2; ++rt) {
        #pragma unroll
        for (int reg = 0; reg < 4; ++reg) {
            float s = sumexp[rt][reg];
            s += __shfl_xor(s, 1);
            s += __shfl_xor(s, 2);
            s += __shfl_xor(s, 4);
            s += __shfl_xor(s, 8);
            if (ccol == 0) ce += __logf(s);       // one lane per (cquad,reg) row
        }
    }
    ce -= diagsum;
    // full-wave sum
    ce += __shfl_xor(ce, 1);
    ce += __shfl_xor(ce, 2);
    ce += __shfl_xor(ce, 4);
    ce += __shfl_xor(ce, 8);
    ce += __shfl_xor(ce, 16);
    ce += __shfl_xor(ce, 32);

    // t_lds no longer needed -> reuse as cross-wave scratch
    __syncthreads();
    float* red = reinterpret_cast<float*>(t_lds);
    if (lane == 0) red[wave] = ce;
    __syncthreads();
    if (tid == 0) {
        float t = 0.f;
        #pragma unroll
        for (int w = 0; w < 8; ++w) t += red[w];
        graph_sums[g] = t;
    }
}

// Kernel 2: deterministic final reduction, out = sum / (G*NA)
__global__ void nlcl_reduce(const float* __restrict__ graph_sums,
                            float* __restrict__ out)
{
    __shared__ float r[4];
    const int tid = threadIdx.x;   // 256 threads
    float v = graph_sums[tid];
    v += __shfl_xor(v, 1);
    v += __shfl_xor(v, 2);
    v += __shfl_xor(v, 4);
    v += __shfl_xor(v, 8);
    v += __shfl_xor(v, 16);
    v += __shfl_xor(v, 32);
    if ((tid & 63) == 0) r[tid >> 6] = v;
    __syncthreads();
    if (tid == 0)
        out[0] = (r[0] + r[1] + r[2] + r[3]) * (1.0f / ((float)G_NUM * (float)NAUG));
}

extern "C" void kernel_launch(void* const* d_in, const int* in_sizes, int n_in,
                              void* d_out, int out_size, void* d_ws, size_t ws_size,
                              hipStream_t stream) {
    (void)in_sizes; (void)n_in; (void)out_size; (void)ws_size;
    const float* student = (const float*)d_in[0];
    const float* teacher = (const float*)d_in[1];
    const int*   kept    = (const int*)d_in[2];
    float* gs  = (float*)d_ws;
    float* out = (float*)d_out;

    nlcl_main<<<G_NUM, 512, 0, stream>>>(student, teacher, kept, gs);
    nlcl_reduce<<<1, 256, 0, stream>>>(gs, out);
}

// Round 2
// 24.452 us; speedup vs baseline: 1.0108x; 1.0108x over previous
//
#include <hip/hip_runtime.h>
#include <hip/hip_bf16.h>

using f32x4  = __attribute__((ext_vector_type(4))) float;
using bf16x8 = __attribute__((ext_vector_type(8))) short;

constexpr int   G_NUM = 256;
constexpr int   NAUG  = 256;
constexpr int   NORIG = 512;
constexpr int   DIM   = 128;
constexpr float INV_T = 10.0f;

// round-to-nearest-even f32 -> bf16 bits
__device__ __forceinline__ short f32_to_bf16_bits(float x) {
    unsigned u = __float_as_uint(x);
    u += 0x7fffu + ((u >> 16) & 1u);
    return (short)(u >> 16);
}

// 512 blocks = 2 per graph (row-split: each block owns 128 student rows).
// 512 threads = 8 waves; wave w owns 16 rows. Teacher tile (256 aligned rows,
// gathered+normalized bf16) in 64KB XOR-swizzled LDS per block.
// __launch_bounds__(512,4): 4 waves/EU -> 2 blocks/CU (LDS 2x64KB <= 160KB).
__global__ __launch_bounds__(512, 4) void nlcl_main(
    const float* __restrict__ student,
    const float* __restrict__ teacher,
    const int*   __restrict__ kept,
    float*       __restrict__ block_sums)
{
    __shared__ short t_lds[NAUG * DIM]; // [256 rows][128 bf16], swizzled, 64KB

    const int bid = blockIdx.x;
    // XCD-bijective swizzle (512 = 8 XCDs x 64): logical pairs (2g,2g+1) on same XCD
    const int logical = (bid & 7) * 64 + (bid >> 3);
    const int g    = logical >> 1;
    const int half = logical & 1;

    const int tid  = threadIdx.x;
    const int lane = tid & 63;
    const int wave = tid >> 6;        // 0..7
    const int rbase = half * 128;     // this block's student-row window

    const float* s_base = student + (size_t)g * NAUG * DIM;
    const float* t_base = teacher + (size_t)g * NORIG * DIM;
    const int*   k_base = kept + g * NAUG;

    const int ccol  = lane & 15;      // col within 16x16 tile / frag row select
    const int cquad = lane >> 4;      // 0..3, selects k-subchunk

    // ---------------- Phase 0: hoist kept-index loads (longest dep chain) ----------------
    const int hw = tid >> 5;          // 0..15 (half-wave id)
    const int hl = tid & 31;
    int idxv[16];
    #pragma unroll
    for (int it = 0; it < 16; ++it) idxv[it] = k_base[it * 16 + hw];

    // ---------------- Phase 1: student -> normalized bf16 A-fragments ----------------
    // lane holds s[row = rbase + wave*16 + ccol][d = kc*32 + cquad*8 + 0..7]
    bf16x8 afrag[4];
    {
        const int row = rbase + wave * 16 + ccol;
        const float* rp = s_base + row * DIM;
        float sf[4][8];
        #pragma unroll
        for (int kc = 0; kc < 4; ++kc) {
            const int d0 = kc * 32 + cquad * 8;
            const float4 a = *reinterpret_cast<const float4*>(rp + d0);
            const float4 b = *reinterpret_cast<const float4*>(rp + d0 + 4);
            sf[kc][0] = a.x; sf[kc][1] = a.y; sf[kc][2] = a.z; sf[kc][3] = a.w;
            sf[kc][4] = b.x; sf[kc][5] = b.y; sf[kc][6] = b.z; sf[kc][7] = b.w;
        }
        float ss = 0.f;
        #pragma unroll
        for (int kc = 0; kc < 4; ++kc)
            #pragma unroll
            for (int e = 0; e < 8; ++e) ss += sf[kc][e] * sf[kc][e];
        // lanes {l, l^16, l^32, l^48} share a row -> combine
        ss += __shfl_xor(ss, 16);
        ss += __shfl_xor(ss, 32);
        const float scale = rsqrtf(fmaxf(ss, 1e-24f));
        #pragma unroll
        for (int kc = 0; kc < 4; ++kc)
            #pragma unroll
            for (int e = 0; e < 8; ++e)
                afrag[kc][e] = f32_to_bf16_bits(sf[kc][e] * scale);
    }

    // ---------------- Phase 2: teacher gather+normalize -> swizzled bf16 LDS ----------------
    // half-wave per row: 32 lanes x float4 = 512B row
    {
        char* tl = reinterpret_cast<char*>(t_lds);
        #pragma unroll
        for (int it = 0; it < 16; ++it) {
            const int j   = it * 16 + hw;          // 0..255
            const float* rp = t_base + (size_t)idxv[it] * DIM;
            const float4 v = *reinterpret_cast<const float4*>(rp + hl * 4);
            float ss = v.x * v.x + v.y * v.y + v.z * v.z + v.w * v.w;
            ss += __shfl_xor(ss, 1);
            ss += __shfl_xor(ss, 2);
            ss += __shfl_xor(ss, 4);
            ss += __shfl_xor(ss, 8);
            ss += __shfl_xor(ss, 16);
            const float scale = rsqrtf(fmaxf(ss, 1e-24f));
            short4 o;
            o.x = f32_to_bf16_bits(v.x * scale);
            o.y = f32_to_bf16_bits(v.y * scale);
            o.z = f32_to_bf16_bits(v.z * scale);
            o.w = f32_to_bf16_bits(v.w * scale);
            // row j, bytes [hl*8, hl*8+8), XOR-swizzled within row (bits 4..6)
            const int byte = j * 256 + ((hl * 8) ^ ((j & 7) << 4));
            *reinterpret_cast<short4*>(tl + byte) = o;
        }
    }
    __syncthreads();

    // ---------------- Phase 3: MFMA + softmax-sum + diagonal ----------------
    float sumexp[4] = {0.f, 0.f, 0.f, 0.f};
    float diagsum = 0.f;
    const char* tl = reinterpret_cast<const char*>(t_lds);

    for (int ct = 0; ct < 16; ++ct) {
        f32x4 acc = {0.f, 0.f, 0.f, 0.f};
        const int j = ct * 16 + ccol;             // teacher row = score col
        #pragma unroll
        for (int kc = 0; kc < 4; ++kc) {
            const int byte = j * 256 + (((kc * 64) + (cquad * 16)) ^ ((j & 7) << 4));
            const bf16x8 b = *reinterpret_cast<const bf16x8*>(tl + byte);
            acc = __builtin_amdgcn_mfma_f32_16x16x32_bf16(afrag[kc], b, acc, 0, 0, 0);
        }
        #pragma unroll
        for (int reg = 0; reg < 4; ++reg) {
            const int row = rbase + wave * 16 + cquad * 4 + reg;
            const float l = acc[reg] * INV_T;
            sumexp[reg] += __expf(l);
            if (j == row) diagsum += l;
        }
    }

    // ---------------- Phase 4: reduce: sum_i log(sumexp_i) - sum_i diag_i ----------------
    float ce = 0.f;
    #pragma unroll
    for (int reg = 0; reg < 4; ++reg) {
        float s = sumexp[reg];
        s += __shfl_xor(s, 1);
        s += __shfl_xor(s, 2);
        s += __shfl_xor(s, 4);
        s += __shfl_xor(s, 8);
        if (ccol == 0) ce += __logf(s);           // one lane per (cquad,reg) row
    }
    ce -= diagsum;
    // full-wave sum
    ce += __shfl_xor(ce, 1);
    ce += __shfl_xor(ce, 2);
    ce += __shfl_xor(ce, 4);
    ce += __shfl_xor(ce, 8);
    ce += __shfl_xor(ce, 16);
    ce += __shfl_xor(ce, 32);

    // t_lds no longer needed -> reuse as cross-wave scratch
    __syncthreads();
    float* red = reinterpret_cast<float*>(t_lds);
    if (lane == 0) red[wave] = ce;
    __syncthreads();
    if (tid == 0) {
        float t = 0.f;
        #pragma unroll
        for (int w = 0; w < 8; ++w) t += red[w];
        block_sums[bid] = t;
    }
}

// Final deterministic reduction over 512 block partials; out = sum / (G*NA)
__global__ void nlcl_reduce(const float* __restrict__ block_sums,
                            float* __restrict__ out)
{
    __shared__ float r[8];
    const int tid = threadIdx.x;   // 512 threads
    float v = block_sums[tid];
    v += __shfl_xor(v, 1);
    v += __shfl_xor(v, 2);
    v += __shfl_xor(v, 4);
    v += __shfl_xor(v, 8);
    v += __shfl_xor(v, 16);
    v += __shfl_xor(v, 32);
    if ((tid & 63) == 0) r[tid >> 6] = v;
    __syncthreads();
    if (tid == 0) {
        float t = 0.f;
        #pragma unroll
        for (int w = 0; w < 8; ++w) t += r[w];
        out[0] = t * (1.0f / ((float)G_NUM * (float)NAUG));
    }
}

extern "C" void kernel_launch(void* const* d_in, const int* in_sizes, int n_in,
                              void* d_out, int out_size, void* d_ws, size_t ws_size,
                              hipStream_t stream) {
    (void)in_sizes; (void)n_in; (void)out_size; (void)ws_size;
    const float* student = (const float*)d_in[0];
    const float* teacher = (const float*)d_in[1];
    const int*   kept    = (const int*)d_in[2];
    float* bs  = (float*)d_ws;
    float* out = (float*)d_out;

    nlcl_main<<<512, 512, 0, stream>>>(student, teacher, kept, bs);
    nlcl_reduce<<<1, 512, 0, stream>>>(bs, out);
}